// Round 7
// baseline (154.541 us; speedup 1.0000x reference)
//
#include <hip/hip_runtime.h>
#include <math.h>

#define B_ROWS 4096
#define T_COLS 4096
#define NTHREADS 256
#define WPB (NTHREADS / 64)       // 4 waves per block, one ROW per WAVE
#define NBLOCKS (B_ROWS / WPB)    // 1024 blocks = 4/CU = 16 waves/CU (grid fully resident)

// Force a (wave-uniform) float into an SGPR.
__device__ __forceinline__ float rfl(float v) {
    return __int_as_float(__builtin_amdgcn_readfirstlane(__float_as_int(v)));
}

#define STEP(z, xv) fmaf(beta, (z), fmaf(alpha, (xv) * (xv), omega))
#define SQ(z) __builtin_amdgcn_sqrtf(z)

__global__ __launch_bounds__(NTHREADS, 4) void garch_fused(
    const float* __restrict__ x,
    const float* __restrict__ p_omega_log,
    const float* __restrict__ p_alpha_log,
    const float* __restrict__ p_beta_log,
    float* __restrict__ out)
{
    const int lane = threadIdx.x & 63;
    const int wv   = threadIdx.x >> 6;
    const long row = (long)blockIdx.x * WPB + wv;

    const float4* xr4 = reinterpret_cast<const float4*>(x + row * T_COLS) + lane * 16;

    // ---- Uniform scalar parameter work -> SGPRs ----
    float ea_p  = expf(p_alpha_log[0]);
    float eb_p  = expf(p_beta_log[0]);
    float denom = 1.0f + ea_p + eb_p;
    float omega = rfl(expf(p_omega_log[0]));
    float alpha = rfl(ea_p / denom);
    float beta  = rfl(eb_p / denom);
    float beta2  = beta * beta;
    float beta4  = beta2 * beta2;
    float beta8  = beta4 * beta4;
    float beta16 = beta8 * beta8;
    float beta32 = beta16 * beta16;
    float beta31 = beta16 * beta8 * beta4 * beta2 * beta;

    // ================= PASS 1: streaming partials (no arrays) =================
    // Two independent chains, float4-aligned:
    //   Z_A: zero-init chain over xs[0..30]   (31 steps, stream A = f4 0..7)
    //   Z_B: zero-init chain over xs[32..62]  (31 steps, stream B = f4 8..15)
    // xs[31] (A f4#7 .w) and xs[63] (B f4#7 .w) are saved as carries.
    float sum0 = 0.0f, sum1 = 0.0f, ssq0 = 0.0f, ssq1 = 0.0f;
    float zA = 0.0f, zB = 0.0f;
    float x31, x63;
#pragma unroll
    for (int r = 0; r < 8; ++r) {
        float4 a = xr4[r];
        float4 b = xr4[r + 8];
        sum0 += (a.x + a.y) + (a.z + a.w);
        sum1 += (b.x + b.y) + (b.z + b.w);
        ssq0 = fmaf(a.x, a.x, ssq0); ssq0 = fmaf(a.y, a.y, ssq0);
        ssq0 = fmaf(a.z, a.z, ssq0); ssq0 = fmaf(a.w, a.w, ssq0);
        ssq1 = fmaf(b.x, b.x, ssq1); ssq1 = fmaf(b.y, b.y, ssq1);
        ssq1 = fmaf(b.z, b.z, ssq1); ssq1 = fmaf(b.w, b.w, ssq1);
        if (r < 7) {
            zA = STEP(zA, a.x); zA = STEP(zA, a.y); zA = STEP(zA, a.z); zA = STEP(zA, a.w);
            zB = STEP(zB, b.x); zB = STEP(zB, b.y); zB = STEP(zB, b.z); zB = STEP(zB, b.w);
        } else {
            zA = STEP(zA, a.x); zA = STEP(zA, a.y); zA = STEP(zA, a.z); x31 = a.w;
            zB = STEP(zB, b.x); zB = STEP(zB, b.y); zB = STEP(zB, b.z); x63 = b.w;
        }
    }
    float s1 = sum0 + sum1;
    float s2 = ssq0 + ssq1;

    // prev = x[64L-1] (lane-1's x63); undefined-but-unused for lane 0.
    float prev = __shfl_up(x63, 1);
    float u = fmaf(alpha, prev * prev, omega);   // state after the prev-step
    float v = fmaf(alpha, x31 * x31, omega);     // contribution of xs[31]

    // Half-A segment map (outputs [0..31]):
    //   lane 0 : 31 steps,  aA = beta^31, bA = Z_A
    //   lane>0 : 32 steps,  aA = beta^32, bA = beta^31*u + Z_A
    float aA = (lane == 0) ? beta31 : beta32;
    float bA = (lane == 0) ? zA : fmaf(beta31, u, zA);

    // Full 64-element map: A, then xs[31]-step, then B (31 steps):
    //   s_out = aA*b32*e + b32*bA + b31*v + Z_B
    float ia = aA * beta32;
    float ib = fmaf(beta32, bA, fmaf(beta31, v, zB));

    // ---- Wave-level reduction (sum, ssq) ----
#pragma unroll
    for (int d = 32; d > 0; d >>= 1) {
        s1 += __shfl_xor(s1, d);
        s2 += __shfl_xor(s2, d);
    }
    float s0 = (s2 - s1 * s1 * (1.0f / T_COLS)) * (1.0f / (T_COLS - 1));
    s0 = fmaxf(s0, 0.0f);

    // ---- Wave-level inclusive affine scan over (ia, ib) ----
#pragma unroll
    for (int d = 1; d < 64; d <<= 1) {
        float pa = __shfl_up(ia, d);
        float pb = __shfl_up(ib, d);
        if (lane >= d) { ib = fmaf(ia, pb, ib); ia = ia * pa; }
    }

    // Exclusive prefix -> eA = sigma2[64L-1] (s0 for lane 0).
    float pea = __shfl_up(ia, 1);
    float peb = __shfl_up(ib, 1);
    if (lane == 0) { pea = 1.0f; peb = 0.0f; }
    float eA = fmaf(pea, s0, peb);
    float eB = fmaf(aA, eA, bA);                 // sigma2[64L+31]

    // ================= PASS 2: re-load (L2/L3-warm) + recompute + store =======
    // Two interleaved dependent chains (A from eA, B from eB) for 2x ILP;
    // per round: 2 float4 loads, 8 STEP, 8 sqrt, 2 float4 stores.
    float4* orow4 = reinterpret_cast<float4*>(out + row * T_COLS) + lane * 16;

    float zc = eA, zd = eB;
    float carryA = prev;                          // input for output 4j (j=0: x[64L-1])
    float carryB = x31;                           // input for output 4j+32
#pragma unroll
    for (int j = 0; j < 8; ++j) {
        float4 a = xr4[j];
        float4 b = xr4[j + 8];
        float4 qa, qb;

        if (j == 0 && lane == 0) {
            // output 0 is s0 itself (no step)
        } else {
            zc = STEP(zc, carryA);
        }
        qa.x = SQ(zc);
        zd = STEP(zd, carryB);  qb.x = SQ(zd);
        zc = STEP(zc, a.x);     qa.y = SQ(zc);
        zd = STEP(zd, b.x);     qb.y = SQ(zd);
        zc = STEP(zc, a.y);     qa.z = SQ(zc);
        zd = STEP(zd, b.y);     qb.z = SQ(zd);
        zc = STEP(zc, a.z);     qa.w = SQ(zc);
        zd = STEP(zd, b.z);     qb.w = SQ(zd);
        carryA = a.w;
        carryB = b.w;

        orow4[j]     = qa;
        orow4[j + 8] = qb;
    }
}

extern "C" void kernel_launch(void* const* d_in, const int* in_sizes, int n_in,
                              void* d_out, int out_size, void* d_ws, size_t ws_size,
                              hipStream_t stream) {
    const float* x         = (const float*)d_in[0];
    const float* omega_log = (const float*)d_in[1];
    const float* alpha_log = (const float*)d_in[2];
    const float* beta_log  = (const float*)d_in[3];
    float* out = (float*)d_out;

    garch_fused<<<NBLOCKS, NTHREADS, 0, stream>>>(x, omega_log, alpha_log, beta_log, out);
}

// Round 8
// 121.583 us; speedup vs baseline: 1.2711x; 1.2711x over previous
//
#include <hip/hip_runtime.h>
#include <math.h>

#define B_ROWS 4096
#define T_COLS 4096
#define NTHREADS 256
#define WPB 4                     // 4 waves per block, one ROW per WAVE (no barriers)
#define NBLOCKS (B_ROWS / WPB)    // 1024 blocks = 4/CU resident = 16 waves/CU
#define NSTRIPE 16                // 16 stripes of 256 elements; 1 float4 per lane per stripe

// Force a (wave-uniform) float into an SGPR.
__device__ __forceinline__ float rfl(float v) {
    return __int_as_float(__builtin_amdgcn_readfirstlane(__float_as_int(v)));
}

#define STEP(z, xv) fmaf(beta, (z), fmaf(alpha, (xv) * (xv), omega))
#define SQ(z) __builtin_amdgcn_sqrtf(z)

__global__ __launch_bounds__(NTHREADS, 4) void garch_fused(
    const float* __restrict__ x,
    const float* __restrict__ p_omega_log,
    const float* __restrict__ p_alpha_log,
    const float* __restrict__ p_beta_log,
    float* __restrict__ out)
{
    const int lane = threadIdx.x & 63;
    const int wv   = threadIdx.x >> 6;
    const long row = (long)blockIdx.x * WPB + wv;

    const float4* X4 = reinterpret_cast<const float4*>(x + row * T_COLS);
    float4*       O4 = reinterpret_cast<float4*>(out + row * T_COLS);

    // ---- Uniform scalar parameter work -> SGPRs ----
    float ea_p  = expf(p_alpha_log[0]);
    float eb_p  = expf(p_beta_log[0]);
    float denom = 1.0f + ea_p + eb_p;
    float omega = rfl(expf(p_omega_log[0]));
    float alpha = rfl(ea_p / denom);
    float beta  = rfl(eb_p / denom);
    float beta2 = beta * beta;
    float beta3 = beta2 * beta;
    float beta4 = beta2 * beta2;

    // ================= PASS 1: variance (pure accumulator loop) ==============
    // 16 independent dwordx4 per lane, nothing but accumulators consuming them:
    // the compiler pipelines this shape reliably (reduction idiom).
    float sum = 0.0f, ssq = 0.0f;
#pragma unroll
    for (int s = 0; s < NSTRIPE; ++s) {
        float4 a = X4[64 * s + lane];
        sum += (a.x + a.y) + (a.z + a.w);
        ssq = fmaf(a.x, a.x, ssq); ssq = fmaf(a.y, a.y, ssq);
        ssq = fmaf(a.z, a.z, ssq); ssq = fmaf(a.w, a.w, ssq);
    }
#pragma unroll
    for (int d = 32; d > 0; d >>= 1) {
        sum += __shfl_xor(sum, d);
        ssq += __shfl_xor(ssq, d);
    }
    float s0 = (ssq - sum * sum * (1.0f / T_COLS)) * (1.0f / (T_COLS - 1));
    s0 = fmaxf(s0, 0.0f);

    // ================= PASS 2: striped scan + recompute + store ==============
    // Per stripe: reload (L2-warm, same wave, µs-scale reuse distance), build
    // per-lane 4-step affine map, wave-scan it (independent of E), apply the
    // serial cross-stripe state E only in a short tail (broadcast + fma).
    float E = s0;            // sigma2 entering the stripe (s0 = sigma2[0] for s=0)
    float carryX = 0.0f;     // x[256*s - 1], unused at s=0
    float4 a = X4[lane];     // prefetch stripe 0
#pragma unroll
    for (int s = 0; s < NSTRIPE; ++s) {
        // One-deep software pipeline: next stripe's load issued before this
        // stripe's compute (consumed only next iteration -> cannot be sunk).
        float4 an = a;
        if (s + 1 < NSTRIPE) an = X4[64 * (s + 1) + lane];

        // x[256s + 4*lane - 1]: lane-1's .w, or the stripe carry.
        float xm1 = __shfl_up(a.w, 1);
        if (lane == 0) xm1 = carryX;

        // Per-lane zero-init affine map over this lane's 4 steps.
        // s==0, lane==0: outputs [0..3], out0 = E itself -> 3 steps over x0..x2.
        float ia, ib;
        if (s == 0 && lane == 0) {
            float zb = fmaf(alpha, a.x * a.x, omega);
            zb = STEP(zb, a.y); zb = STEP(zb, a.z);
            ia = beta3; ib = zb;
        } else {
            float zb = fmaf(alpha, xm1 * xm1, omega);
            zb = STEP(zb, a.x); zb = STEP(zb, a.y); zb = STEP(zb, a.z);
            ia = beta4; ib = zb;
        }

        // Wave-level inclusive affine scan (independent of E).
#pragma unroll
        for (int d = 1; d < 64; d <<= 1) {
            float pa = __shfl_up(ia, d);
            float pb = __shfl_up(ib, d);
            if (lane >= d) { ib = fmaf(ia, pb, ib); ia = ia * pa; }
        }

        // Exclusive prefix -> per-lane entry state.
        float pea = __shfl_up(ia, 1);
        float peb = __shfl_up(ib, 1);
        if (lane == 0) { pea = 1.0f; peb = 0.0f; }
        float e = fmaf(pea, E, peb);

        // Recompute 4 outputs + sqrt, store coalesced.
        float4 q;
        float z;
        if (s == 0 && lane == 0) { z = e; }            // out 0 = s0
        else                     { z = STEP(e, xm1); }
        q.x = SQ(z);
        z = STEP(z, a.x); q.y = SQ(z);
        z = STEP(z, a.y); q.z = SQ(z);
        z = STEP(z, a.z); q.w = SQ(z);
        O4[64 * s + lane] = q;

        // Cross-stripe carries (the only serial dependence): E' = ia63*E + ib63.
        float ia63 = __shfl(ia, 63);
        float ib63 = __shfl(ib, 63);
        E = fmaf(ia63, E, ib63);
        carryX = __shfl(a.w, 63);
        a = an;
    }
}

extern "C" void kernel_launch(void* const* d_in, const int* in_sizes, int n_in,
                              void* d_out, int out_size, void* d_ws, size_t ws_size,
                              hipStream_t stream) {
    const float* x         = (const float*)d_in[0];
    const float* omega_log = (const float*)d_in[1];
    const float* alpha_log = (const float*)d_in[2];
    const float* beta_log  = (const float*)d_in[3];
    float* out = (float*)d_out;

    garch_fused<<<NBLOCKS, NTHREADS, 0, stream>>>(x, omega_log, alpha_log, beta_log, out);
}